// Round 1
// baseline (405.148 us; speedup 1.0000x reference)
//
#include <hip/hip_runtime.h>
#include <math.h>

// Problem constants (from reference setup_inputs)
#define BNUM 16
#define NNUM 4096
#define DNUM 1024
#define CNUM 4
#define HNUM 512

#define SCH   64              // N-chunks per bag
#define ROWS  (NNUM / SCH)    // 64 rows per workgroup
#define RPW   (ROWS / 4)      // 16 rows per wave (4 waves / 256-thread block)

// Workspace layout (in floats):
//  partials: [BNUM*SCH] x PSTRIDE  {sum[1024], max[1024], acc[1024], m, l, pad}
//  x features: [BNUM][3*DNUM]
//  Weff: [3*DNUM][4]
#define PSTRIDE 3080
#define NPART   (BNUM * SCH)
#define XOFF    ((size_t)NPART * PSTRIDE)
#define WOFF    (XOFF + (size_t)BNUM * 3 * DNUM)

#define NEG_INF (-__builtin_inff())

// ---------------------------------------------------------------------------
// K1: one streaming pass over bags. Each block = (bag b, chunk) of 64 rows.
// 4 waves/block, each wave handles 16 consecutive rows. Lane owns 16 d's
// (4 x float4 at d = seg*256 + lane*4). Per row: coalesced 4KB read,
// running sum/max per d, wave-allreduce dot(bags_row, query), online softmax
// accumulate. Block-combines 4 waves through 16KB LDS, writes one partial.
// ---------------------------------------------------------------------------
__global__ __launch_bounds__(256) void k_mainpass(const float* __restrict__ bags,
                                                  const float* __restrict__ query,
                                                  float* __restrict__ ws) {
    const int chunk = blockIdx.x;
    const int b     = blockIdx.y;
    const int tid   = threadIdx.x;
    const int wave  = tid >> 6;
    const int lane  = tid & 63;

    const float4* q4 = (const float4*)query;
    float4 q[4];
#pragma unroll
    for (int s = 0; s < 4; ++s) q[s] = q4[s * 64 + lane];

    float4 sum[4], mx[4], acc[4];
#pragma unroll
    for (int s = 0; s < 4; ++s) {
        sum[s] = make_float4(0.f, 0.f, 0.f, 0.f);
        acc[s] = make_float4(0.f, 0.f, 0.f, 0.f);
        mx[s]  = make_float4(NEG_INF, NEG_INF, NEG_INF, NEG_INF);
    }
    float m = NEG_INF, l = 0.f;

    const int n0 = chunk * ROWS + wave * RPW;
    const float4* base = (const float4*)(bags + (size_t)b * NNUM * DNUM);

    for (int r = 0; r < RPW; ++r) {
        const float4* row = base + (size_t)(n0 + r) * (DNUM / 4);
        float4 v[4];
#pragma unroll
        for (int s = 0; s < 4; ++s) v[s] = row[s * 64 + lane];

        // partial dot with query, then wave-wide allreduce
        float pd = 0.f;
#pragma unroll
        for (int s = 0; s < 4; ++s)
            pd += v[s].x * q[s].x + v[s].y * q[s].y + v[s].z * q[s].z + v[s].w * q[s].w;
#pragma unroll
        for (int off = 32; off; off >>= 1) pd += __shfl_xor(pd, off, 64);

        // online softmax update (all lanes identical m,l)
        const float mnew  = fmaxf(m, pd);
        const float alpha = __expf(m - mnew);   // m=-inf first iter -> 0
        const float w     = __expf(pd - mnew);
        l = l * alpha + w;
        m = mnew;

#pragma unroll
        for (int s = 0; s < 4; ++s) {
            sum[s].x += v[s].x; sum[s].y += v[s].y; sum[s].z += v[s].z; sum[s].w += v[s].w;
            mx[s].x = fmaxf(mx[s].x, v[s].x); mx[s].y = fmaxf(mx[s].y, v[s].y);
            mx[s].z = fmaxf(mx[s].z, v[s].z); mx[s].w = fmaxf(mx[s].w, v[s].w);
            acc[s].x = acc[s].x * alpha + w * v[s].x;
            acc[s].y = acc[s].y * alpha + w * v[s].y;
            acc[s].z = acc[s].z * alpha + w * v[s].z;
            acc[s].w = acc[s].w * alpha + w * v[s].w;
        }
    }

    // ---- block combine across 4 waves via reused 16KB LDS buffer ----
    __shared__ float buf[4][DNUM];
    __shared__ float sm[4], sl[4];
    if (lane == 0) { sm[wave] = m; sl[wave] = l; }

    float* wsp = ws + (size_t)(b * SCH + chunk) * PSTRIDE;

    // sums
#pragma unroll
    for (int s = 0; s < 4; ++s) ((float4*)(&buf[wave][s * 256]))[lane] = sum[s];
    __syncthreads();
    {
        float4 a0 = ((float4*)buf[0])[tid];
        float4 a1 = ((float4*)buf[1])[tid];
        float4 a2 = ((float4*)buf[2])[tid];
        float4 a3 = ((float4*)buf[3])[tid];
        float4 r;
        r.x = a0.x + a1.x + a2.x + a3.x;
        r.y = a0.y + a1.y + a2.y + a3.y;
        r.z = a0.z + a1.z + a2.z + a3.z;
        r.w = a0.w + a1.w + a2.w + a3.w;
        ((float4*)wsp)[tid] = r;
    }
    __syncthreads();

    // maxes
#pragma unroll
    for (int s = 0; s < 4; ++s) ((float4*)(&buf[wave][s * 256]))[lane] = mx[s];
    __syncthreads();
    {
        float4 a0 = ((float4*)buf[0])[tid];
        float4 a1 = ((float4*)buf[1])[tid];
        float4 a2 = ((float4*)buf[2])[tid];
        float4 a3 = ((float4*)buf[3])[tid];
        float4 r;
        r.x = fmaxf(fmaxf(a0.x, a1.x), fmaxf(a2.x, a3.x));
        r.y = fmaxf(fmaxf(a0.y, a1.y), fmaxf(a2.y, a3.y));
        r.z = fmaxf(fmaxf(a0.z, a1.z), fmaxf(a2.z, a3.z));
        r.w = fmaxf(fmaxf(a0.w, a1.w), fmaxf(a2.w, a3.w));
        ((float4*)(wsp + 1024))[tid] = r;
    }
    __syncthreads();

    // softmax accumulators
#pragma unroll
    for (int s = 0; s < 4; ++s) ((float4*)(&buf[wave][s * 256]))[lane] = acc[s];
    __syncthreads();
    {
        const float m0 = sm[0], m1 = sm[1], m2 = sm[2], m3 = sm[3];
        const float mb = fmaxf(fmaxf(m0, m1), fmaxf(m2, m3));
        const float e0 = __expf(m0 - mb), e1 = __expf(m1 - mb);
        const float e2 = __expf(m2 - mb), e3 = __expf(m3 - mb);
        float4 a0 = ((float4*)buf[0])[tid];
        float4 a1 = ((float4*)buf[1])[tid];
        float4 a2 = ((float4*)buf[2])[tid];
        float4 a3 = ((float4*)buf[3])[tid];
        float4 r;
        r.x = a0.x * e0 + a1.x * e1 + a2.x * e2 + a3.x * e3;
        r.y = a0.y * e0 + a1.y * e1 + a2.y * e2 + a3.y * e3;
        r.z = a0.z * e0 + a1.z * e1 + a2.z * e2 + a3.z * e3;
        r.w = a0.w * e0 + a1.w * e1 + a2.w * e2 + a3.w * e3;
        ((float4*)(wsp + 2048))[tid] = r;
        if (tid == 0) {
            wsp[3072] = mb;
            wsp[3073] = sl[0] * e0 + sl[1] * e1 + sl[2] * e2 + sl[3] * e3;
        }
    }
}

// ---------------------------------------------------------------------------
// K2: combine 64 chunk-partials per bag -> features x[b][3*DNUM].
// grid (BNUM, DNUM/64), 64 threads; thread owns one d.
// ---------------------------------------------------------------------------
__global__ __launch_bounds__(64) void k_combine(float* __restrict__ ws) {
    const int b = blockIdx.x;
    const int d = blockIdx.y * 64 + threadIdx.x;
    const float* pb = ws + (size_t)b * SCH * PSTRIDE;

    float mb = NEG_INF;
    for (int c = 0; c < SCH; ++c) mb = fmaxf(mb, pb[(size_t)c * PSTRIDE + 3072]);
    float lb = 0.f;
    for (int c = 0; c < SCH; ++c)
        lb += pb[(size_t)c * PSTRIDE + 3073] * __expf(pb[(size_t)c * PSTRIDE + 3072] - mb);

    float s = 0.f, mxv = NEG_INF, av = 0.f;
    for (int c = 0; c < SCH; ++c) {
        const float* p = pb + (size_t)c * PSTRIDE;
        s += p[d];
        mxv = fmaxf(mxv, p[1024 + d]);
        av += p[2048 + d] * __expf(p[3072] - mb);
    }
    float* x = ws + XOFF + (size_t)b * 3 * DNUM;
    x[d]            = s * (1.f / NNUM);
    x[DNUM + d]     = mxv;
    x[2 * DNUM + d] = av / lb;
}

// ---------------------------------------------------------------------------
// KA: Weff[3072][4] = W1 @ W2  (head is affine: no activation in reference).
// One wave per W1 row; W2 (8KB) served from L1/L2.
// ---------------------------------------------------------------------------
__global__ __launch_bounds__(256) void k_weff(const float* __restrict__ W1,
                                              const float* __restrict__ W2,
                                              float* __restrict__ ws) {
    const int tid  = threadIdx.x;
    const int wave = tid >> 6, lane = tid & 63;
    const int k    = blockIdx.x * 4 + wave;
    const float*  r  = W1 + (size_t)k * HNUM;
    const float4* w2 = (const float4*)W2;

    float a0 = 0.f, a1 = 0.f, a2 = 0.f, a3 = 0.f;
#pragma unroll
    for (int t = 0; t < 8; ++t) {
        const int j = lane * 8 + t;
        const float  wv = r[j];
        const float4 w  = w2[j];
        a0 += wv * w.x; a1 += wv * w.y; a2 += wv * w.z; a3 += wv * w.w;
    }
#pragma unroll
    for (int off = 32; off; off >>= 1) {
        a0 += __shfl_xor(a0, off, 64);
        a1 += __shfl_xor(a1, off, 64);
        a2 += __shfl_xor(a2, off, 64);
        a3 += __shfl_xor(a3, off, 64);
    }
    if (lane == 0)
        ((float4*)(ws + WOFF))[k] = make_float4(a0, a1, a2, a3);
}

// ---------------------------------------------------------------------------
// KB: out[i][c] = x[i] . Weff[:,c] + (b1 @ W2)[c] + b2[c].  One block per i.
// ---------------------------------------------------------------------------
__global__ __launch_bounds__(256) void k_head(const float* __restrict__ b1,
                                              const float* __restrict__ b2,
                                              const float* __restrict__ W2,
                                              const float* __restrict__ ws,
                                              float* __restrict__ out) {
    const int i   = blockIdx.x;
    const int tid = threadIdx.x;
    const float*  x    = ws + XOFF + (size_t)i * 3 * DNUM;
    const float4* weff = (const float4*)(ws + WOFF);
    const float4* w2   = (const float4*)W2;

    float a0 = 0.f, a1 = 0.f, a2 = 0.f, a3 = 0.f;
    for (int k = tid; k < 3 * DNUM; k += 256) {
        const float  xv = x[k];
        const float4 w  = weff[k];
        a0 += xv * w.x; a1 += xv * w.y; a2 += xv * w.z; a3 += xv * w.w;
    }
    for (int j = tid; j < HNUM; j += 256) {
        const float  bv = b1[j];
        const float4 w  = w2[j];
        a0 += bv * w.x; a1 += bv * w.y; a2 += bv * w.z; a3 += bv * w.w;
    }
#pragma unroll
    for (int off = 32; off; off >>= 1) {
        a0 += __shfl_xor(a0, off, 64);
        a1 += __shfl_xor(a1, off, 64);
        a2 += __shfl_xor(a2, off, 64);
        a3 += __shfl_xor(a3, off, 64);
    }
    __shared__ float red[4][4];
    const int wave = tid >> 6, lane = tid & 63;
    if (lane == 0) { red[wave][0] = a0; red[wave][1] = a1; red[wave][2] = a2; red[wave][3] = a3; }
    __syncthreads();
    if (tid < 4) {
        out[i * 4 + tid] = red[0][tid] + red[1][tid] + red[2][tid] + red[3][tid] + b2[tid];
    }
}

extern "C" void kernel_launch(void* const* d_in, const int* in_sizes, int n_in,
                              void* d_out, int out_size, void* d_ws, size_t ws_size,
                              hipStream_t stream) {
    const float* bags  = (const float*)d_in[0];
    const float* query = (const float*)d_in[1];
    const float* W1    = (const float*)d_in[2];
    const float* b1    = (const float*)d_in[3];
    const float* W2    = (const float*)d_in[4];
    const float* b2    = (const float*)d_in[5];
    float* out = (float*)d_out;
    float* ws  = (float*)d_ws;

    k_weff    <<<(3 * DNUM) / 4,        256, 0, stream>>>(W1, W2, ws);
    k_mainpass<<<dim3(SCH, BNUM),       256, 0, stream>>>(bags, query, ws);
    k_combine <<<dim3(BNUM, DNUM / 64),  64, 0, stream>>>(ws);
    k_head    <<<BNUM,                  256, 0, stream>>>(b1, b2, W2, ws, out);
}

// Round 2
// 393.266 us; speedup vs baseline: 1.0302x; 1.0302x over previous
//
#include <hip/hip_runtime.h>
#include <math.h>

// Problem constants (from reference setup_inputs)
#define BNUM 16
#define NNUM 4096
#define DNUM 1024
#define CNUM 4
#define HNUM 512

#define SCH   64              // N-chunks per bag
#define ROWS  (NNUM / SCH)    // 64 rows per workgroup
#define RPW   (ROWS / 4)      // 16 rows per wave (4 waves / 256-thread block)

// Workspace layout (in floats):
//  partials: [BNUM*SCH] x PSTRIDE  {sum[1024], max[1024], acc[1024], m, l, pad}
//  (gap: legacy x region, unused)
//  Weff: [3*DNUM][4], then bias[4]
#define PSTRIDE 3080
#define NPART   (BNUM * SCH)
#define XOFF    ((size_t)NPART * PSTRIDE)
#define WOFF    (XOFF + (size_t)BNUM * 3 * DNUM)
#define BIASOFF (WOFF + (size_t)3 * DNUM * 4)

#define NEG_INF (-__builtin_inff())

// ---------------------------------------------------------------------------
// K1: one streaming pass over bags. Block = (chunk, bag), 4 waves, each wave
// owns 16 consecutive rows, processed in PAIRS: two independent dot-reduce
// chains overlap the shuffle latency, and the online-softmax rescale is a
// wave-uniform branch taken only on a new running max (~3-4x per 16 rows).
// ---------------------------------------------------------------------------
__global__ __launch_bounds__(256) void k_mainpass(const float* __restrict__ bags,
                                                  const float* __restrict__ query,
                                                  float* __restrict__ ws) {
    const int chunk = blockIdx.x;
    const int b     = blockIdx.y;
    const int tid   = threadIdx.x;
    const int wave  = tid >> 6;
    const int lane  = tid & 63;

    const float4* q4 = (const float4*)query;
    float4 q[4];
#pragma unroll
    for (int s = 0; s < 4; ++s) q[s] = q4[s * 64 + lane];

    float4 sum[4], mx[4], acc[4];
#pragma unroll
    for (int s = 0; s < 4; ++s) {
        sum[s] = make_float4(0.f, 0.f, 0.f, 0.f);
        acc[s] = make_float4(0.f, 0.f, 0.f, 0.f);
        mx[s]  = make_float4(NEG_INF, NEG_INF, NEG_INF, NEG_INF);
    }
    float m = NEG_INF, l = 0.f;

    const int n0 = chunk * ROWS + wave * RPW;
    const float4* base = (const float4*)(bags + (size_t)b * NNUM * DNUM);

    for (int r = 0; r < RPW; r += 2) {
        const float4* rowA = base + (size_t)(n0 + r) * (DNUM / 4);
        const float4* rowB = rowA + (DNUM / 4);
        float4 va[4], vb[4];
#pragma unroll
        for (int s = 0; s < 4; ++s) va[s] = rowA[s * 64 + lane];
#pragma unroll
        for (int s = 0; s < 4; ++s) vb[s] = rowB[s * 64 + lane];

        // two independent partial dots
        float pa = 0.f, pb = 0.f;
#pragma unroll
        for (int s = 0; s < 4; ++s) {
            pa += va[s].x * q[s].x + va[s].y * q[s].y + va[s].z * q[s].z + va[s].w * q[s].w;
            pb += vb[s].x * q[s].x + vb[s].y * q[s].y + vb[s].z * q[s].z + vb[s].w * q[s].w;
        }
        // interleaved wave allreduce (chains overlap)
#pragma unroll
        for (int off = 32; off; off >>= 1) {
            pa += __shfl_xor(pa, off, 64);
            pb += __shfl_xor(pb, off, 64);
        }

        // online softmax: wave-uniform, rarely-taken rescale
        const float mnew = fmaxf(m, fmaxf(pa, pb));
        if (mnew > m) {                       // uniform across lanes (pa,pb reduced)
            const float alpha = __expf(m - mnew);   // m=-inf first time -> 0
            l *= alpha;
#pragma unroll
            for (int s = 0; s < 4; ++s) {
                acc[s].x *= alpha; acc[s].y *= alpha;
                acc[s].z *= alpha; acc[s].w *= alpha;
            }
            m = mnew;
        }
        const float wa = __expf(pa - m);
        const float wb = __expf(pb - m);
        l += wa + wb;

#pragma unroll
        for (int s = 0; s < 4; ++s) {
            sum[s].x += va[s].x + vb[s].x;
            sum[s].y += va[s].y + vb[s].y;
            sum[s].z += va[s].z + vb[s].z;
            sum[s].w += va[s].w + vb[s].w;
            mx[s].x = fmaxf(mx[s].x, fmaxf(va[s].x, vb[s].x));
            mx[s].y = fmaxf(mx[s].y, fmaxf(va[s].y, vb[s].y));
            mx[s].z = fmaxf(mx[s].z, fmaxf(va[s].z, vb[s].z));
            mx[s].w = fmaxf(mx[s].w, fmaxf(va[s].w, vb[s].w));
            acc[s].x += wa * va[s].x + wb * vb[s].x;
            acc[s].y += wa * va[s].y + wb * vb[s].y;
            acc[s].z += wa * va[s].z + wb * vb[s].z;
            acc[s].w += wa * va[s].w + wb * vb[s].w;
        }
    }

    // ---- block combine across 4 waves via reused 16KB LDS buffer ----
    __shared__ float buf[4][DNUM];
    __shared__ float sm[4], sl[4];
    if (lane == 0) { sm[wave] = m; sl[wave] = l; }

    float* wsp = ws + (size_t)(b * SCH + chunk) * PSTRIDE;

    // sums
#pragma unroll
    for (int s = 0; s < 4; ++s) ((float4*)(&buf[wave][s * 256]))[lane] = sum[s];
    __syncthreads();
    {
        float4 a0 = ((float4*)buf[0])[tid];
        float4 a1 = ((float4*)buf[1])[tid];
        float4 a2 = ((float4*)buf[2])[tid];
        float4 a3 = ((float4*)buf[3])[tid];
        float4 r;
        r.x = a0.x + a1.x + a2.x + a3.x;
        r.y = a0.y + a1.y + a2.y + a3.y;
        r.z = a0.z + a1.z + a2.z + a3.z;
        r.w = a0.w + a1.w + a2.w + a3.w;
        ((float4*)wsp)[tid] = r;
    }
    __syncthreads();

    // maxes
#pragma unroll
    for (int s = 0; s < 4; ++s) ((float4*)(&buf[wave][s * 256]))[lane] = mx[s];
    __syncthreads();
    {
        float4 a0 = ((float4*)buf[0])[tid];
        float4 a1 = ((float4*)buf[1])[tid];
        float4 a2 = ((float4*)buf[2])[tid];
        float4 a3 = ((float4*)buf[3])[tid];
        float4 r;
        r.x = fmaxf(fmaxf(a0.x, a1.x), fmaxf(a2.x, a3.x));
        r.y = fmaxf(fmaxf(a0.y, a1.y), fmaxf(a2.y, a3.y));
        r.z = fmaxf(fmaxf(a0.z, a1.z), fmaxf(a2.z, a3.z));
        r.w = fmaxf(fmaxf(a0.w, a1.w), fmaxf(a2.w, a3.w));
        ((float4*)(wsp + 1024))[tid] = r;
    }
    __syncthreads();

    // softmax accumulators
#pragma unroll
    for (int s = 0; s < 4; ++s) ((float4*)(&buf[wave][s * 256]))[lane] = acc[s];
    __syncthreads();
    {
        const float m0 = sm[0], m1 = sm[1], m2 = sm[2], m3 = sm[3];
        const float mb = fmaxf(fmaxf(m0, m1), fmaxf(m2, m3));
        const float e0 = __expf(m0 - mb), e1 = __expf(m1 - mb);
        const float e2 = __expf(m2 - mb), e3 = __expf(m3 - mb);
        float4 a0 = ((float4*)buf[0])[tid];
        float4 a1 = ((float4*)buf[1])[tid];
        float4 a2 = ((float4*)buf[2])[tid];
        float4 a3 = ((float4*)buf[3])[tid];
        float4 r;
        r.x = a0.x * e0 + a1.x * e1 + a2.x * e2 + a3.x * e3;
        r.y = a0.y * e0 + a1.y * e1 + a2.y * e2 + a3.y * e3;
        r.z = a0.z * e0 + a1.z * e1 + a2.z * e2 + a3.z * e3;
        r.w = a0.w * e0 + a1.w * e1 + a2.w * e2 + a3.w * e3;
        ((float4*)(wsp + 2048))[tid] = r;
        if (tid == 0) {
            wsp[3072] = mb;
            wsp[3073] = sl[0] * e0 + sl[1] * e1 + sl[2] * e2 + sl[3] * e3;
        }
    }
}

// ---------------------------------------------------------------------------
// KA: blocks 0..767: Weff[3072][4] = W1 @ W2 (head is affine: no activation).
//     block 768: bias[4] = b1 @ W2 + b2.
// ---------------------------------------------------------------------------
__global__ __launch_bounds__(256) void k_weff(const float* __restrict__ W1,
                                              const float* __restrict__ W2,
                                              const float* __restrict__ b1,
                                              const float* __restrict__ b2,
                                              float* __restrict__ ws) {
    const int tid  = threadIdx.x;
    const int wave = tid >> 6, lane = tid & 63;
    const float4* w2 = (const float4*)W2;

    if (blockIdx.x < 768) {
        const int k = blockIdx.x * 4 + wave;
        const float* r = W1 + (size_t)k * HNUM;
        float a0 = 0.f, a1 = 0.f, a2 = 0.f, a3 = 0.f;
#pragma unroll
        for (int t = 0; t < 8; ++t) {
            const int j = lane * 8 + t;
            const float  wv = r[j];
            const float4 w  = w2[j];
            a0 += wv * w.x; a1 += wv * w.y; a2 += wv * w.z; a3 += wv * w.w;
        }
#pragma unroll
        for (int off = 32; off; off >>= 1) {
            a0 += __shfl_xor(a0, off, 64);
            a1 += __shfl_xor(a1, off, 64);
            a2 += __shfl_xor(a2, off, 64);
            a3 += __shfl_xor(a3, off, 64);
        }
        if (lane == 0)
            ((float4*)(ws + WOFF))[k] = make_float4(a0, a1, a2, a3);
    } else if (wave == 0) {
        float a0 = 0.f, a1 = 0.f, a2 = 0.f, a3 = 0.f;
#pragma unroll
        for (int t = 0; t < 8; ++t) {
            const int j = lane * 8 + t;
            const float  bv = b1[j];
            const float4 w  = w2[j];
            a0 += bv * w.x; a1 += bv * w.y; a2 += bv * w.z; a3 += bv * w.w;
        }
#pragma unroll
        for (int off = 32; off; off >>= 1) {
            a0 += __shfl_xor(a0, off, 64);
            a1 += __shfl_xor(a1, off, 64);
            a2 += __shfl_xor(a2, off, 64);
            a3 += __shfl_xor(a3, off, 64);
        }
        if (lane == 0) {
            float* bias = ws + BIASOFF;
            bias[0] = a0 + b2[0];
            bias[1] = a1 + b2[1];
            bias[2] = a2 + b2[2];
            bias[3] = a3 + b2[3];
        }
    }
}

// ---------------------------------------------------------------------------
// K2 (fused combine+head): one block per bag. Wave 0 merges the 64 chunk
// (m,l) pairs; then all 256 threads stream the 64 partials (thread owns
// 4 d's per section), form features in registers, and dot with Weff rows
// on the fly. Block-reduce to 4 channels.
// ---------------------------------------------------------------------------
__global__ __launch_bounds__(256) void k_finish(const float* __restrict__ ws,
                                                float* __restrict__ out) {
    const int b    = blockIdx.x;
    const int tid  = threadIdx.x;
    const int wave = tid >> 6, lane = tid & 63;

    __shared__ float eS[SCH];
    __shared__ float lbS;
    __shared__ float red[4][4];

    const float* pb = ws + (size_t)b * SCH * PSTRIDE;

    if (wave == 0) {
        const float* p = pb + (size_t)lane * PSTRIDE;
        const float mlane = p[3072];
        const float llane = p[3073];
        float mb = mlane;
#pragma unroll
        for (int off = 32; off; off >>= 1) mb = fmaxf(mb, __shfl_xor(mb, off, 64));
        const float e = __expf(mlane - mb);
        float lb = llane * e;
#pragma unroll
        for (int off = 32; off; off >>= 1) lb += __shfl_xor(lb, off, 64);
        eS[lane] = e;
        if (lane == 0) lbS = lb;
    }
    __syncthreads();
    const float inv_lb = 1.f / lbS;

    float4 s  = make_float4(0.f, 0.f, 0.f, 0.f);
    float4 a  = make_float4(0.f, 0.f, 0.f, 0.f);
    float4 mxv = make_float4(NEG_INF, NEG_INF, NEG_INF, NEG_INF);
    for (int c = 0; c < SCH; ++c) {
        const float* p = pb + (size_t)c * PSTRIDE;
        const float4 sv = ((const float4*)p)[tid];
        const float4 mv = ((const float4*)(p + 1024))[tid];
        const float4 av = ((const float4*)(p + 2048))[tid];
        const float e = eS[c];
        s.x += sv.x; s.y += sv.y; s.z += sv.z; s.w += sv.w;
        mxv.x = fmaxf(mxv.x, mv.x); mxv.y = fmaxf(mxv.y, mv.y);
        mxv.z = fmaxf(mxv.z, mv.z); mxv.w = fmaxf(mxv.w, mv.w);
        a.x += e * av.x; a.y += e * av.y; a.z += e * av.z; a.w += e * av.w;
    }

    const float4* weff = (const float4*)(ws + WOFF);
    float c0 = 0.f, c1 = 0.f, c2 = 0.f, c3 = 0.f;
    const float scm = 1.f / NNUM;
    const float xm[4] = { s.x * scm, s.y * scm, s.z * scm, s.w * scm };
    const float xx[4] = { mxv.x, mxv.y, mxv.z, mxv.w };
    const float xa[4] = { a.x * inv_lb, a.y * inv_lb, a.z * inv_lb, a.w * inv_lb };
#pragma unroll
    for (int k = 0; k < 4; ++k) {
        const float4 w = weff[tid * 4 + k];
        c0 += xm[k] * w.x; c1 += xm[k] * w.y; c2 += xm[k] * w.z; c3 += xm[k] * w.w;
    }
#pragma unroll
    for (int k = 0; k < 4; ++k) {
        const float4 w = weff[DNUM + tid * 4 + k];
        c0 += xx[k] * w.x; c1 += xx[k] * w.y; c2 += xx[k] * w.z; c3 += xx[k] * w.w;
    }
#pragma unroll
    for (int k = 0; k < 4; ++k) {
        const float4 w = weff[2 * DNUM + tid * 4 + k];
        c0 += xa[k] * w.x; c1 += xa[k] * w.y; c2 += xa[k] * w.z; c3 += xa[k] * w.w;
    }
#pragma unroll
    for (int off = 32; off; off >>= 1) {
        c0 += __shfl_xor(c0, off, 64);
        c1 += __shfl_xor(c1, off, 64);
        c2 += __shfl_xor(c2, off, 64);
        c3 += __shfl_xor(c3, off, 64);
    }
    if (lane == 0) { red[wave][0] = c0; red[wave][1] = c1; red[wave][2] = c2; red[wave][3] = c3; }
    __syncthreads();
    if (tid < 4) {
        const float* bias = ws + BIASOFF;
        out[b * 4 + tid] = red[0][tid] + red[1][tid] + red[2][tid] + red[3][tid] + bias[tid];
    }
}

extern "C" void kernel_launch(void* const* d_in, const int* in_sizes, int n_in,
                              void* d_out, int out_size, void* d_ws, size_t ws_size,
                              hipStream_t stream) {
    const float* bags  = (const float*)d_in[0];
    const float* query = (const float*)d_in[1];
    const float* W1    = (const float*)d_in[2];
    const float* b1    = (const float*)d_in[3];
    const float* W2    = (const float*)d_in[4];
    const float* b2    = (const float*)d_in[5];
    float* out = (float*)d_out;
    float* ws  = (float*)d_ws;

    k_weff    <<<769,             256, 0, stream>>>(W1, W2, b1, b2, ws);
    k_mainpass<<<dim3(SCH, BNUM), 256, 0, stream>>>(bags, query, ws);
    k_finish  <<<BNUM,            256, 0, stream>>>(ws, out);
}